// Round 6
// baseline (153.242 us; speedup 1.0000x reference)
//
#include <hip/hip_runtime.h>

typedef unsigned short u16;
typedef unsigned int u32;
typedef float f32x4 __attribute__((ext_vector_type(4)));
typedef short s16x8 __attribute__((ext_vector_type(8)));

#define LSEQ 2048
#define QIN 512
#define VIN 1024
#define KCAT 704
#define KEFF 2560
#define NORMS 0.10206207261596575f  // 1/sqrt(96)

__device__ __forceinline__ u16 f2bf(float f) {
  u32 u = __float_as_uint(f);
  u = (u + 0x7fffu + ((u >> 16) & 1u)) >> 16;  // RNE
  return (u16)u;
}
__device__ __forceinline__ float bf2f(u16 v) {
  return __uint_as_float(((u32)v) << 16);
}

__device__ __forceinline__ s16x8 load8cvt(const float* __restrict__ p) {
  float4 a = *(const float4*)p;
  float4 b = *(const float4*)(p + 4);
  s16x8 r;
  r[0] = (short)f2bf(a.x); r[1] = (short)f2bf(a.y);
  r[2] = (short)f2bf(a.z); r[3] = (short)f2bf(a.w);
  r[4] = (short)f2bf(b.x); r[5] = (short)f2bf(b.y);
  r[6] = (short)f2bf(b.z); r[7] = (short)f2bf(b.w);
  return r;
}

// Fragment-linear index for a weight matrix W[N=96][K]:
// element W[o][k] -> ((kc*6 + nt)*64 + kg*16 + ln)*8 + j
__device__ __forceinline__ size_t wfrag_idx(int o, int k) {
  int kc = k >> 5, kg = (k >> 3) & 3, j = k & 7;
  int nt = o >> 4, ln = o & 15;
  return ((size_t)(kc * 6 + nt) * 64 + kg * 16 + ln) * 8 + j;
}

// ---------------------------------------------------------------------------
// Kernel 0: transpose conv weights to j-contiguous: c3t[t][c][j], c5t[t][c][j]
// ---------------------------------------------------------------------------
__global__ __launch_bounds__(256) void prep_transpose(
    const float* __restrict__ cn3_w, const float* __restrict__ cn5_w,
    float* __restrict__ c3t, float* __restrict__ c5t) {
  int idx = blockIdx.x * 256 + threadIdx.x;
  if (idx < 3 * 512 * 96) {
    int t = idx / (512 * 96);
    int rem = idx - t * 512 * 96;
    int c = rem / 96, j = rem - c * 96;
    c3t[idx] = cn3_w[(j * 512 + c) * 3 + t];
  } else {
    int i2 = idx - 3 * 512 * 96;   // < 5*512*96
    int t = i2 / (512 * 96);
    int rem = i2 - t * 512 * 96;
    int c = rem / 96, j = rem - c * 96;
    c5t[i2] = cn5_w[(j * 512 + c) * 5 + t];
  }
}

// ---------------------------------------------------------------------------
// Kernel 1: fold conv3/conv5 + k_w into W_eff (frag layout) + b_eff;
// convert q_w / v_w to frag-bf16.
// ---------------------------------------------------------------------------
__global__ __launch_bounds__(256) void prep_fold(
    const float* __restrict__ q_w, const float* __restrict__ k_w,
    const float* __restrict__ k_b, const float* __restrict__ v_w,
    const float* __restrict__ c3t, const float* __restrict__ cn3_b,
    const float* __restrict__ c5t, const float* __restrict__ cn5_b,
    u16* __restrict__ wefff, float* __restrict__ beff,
    u16* __restrict__ qwf, u16* __restrict__ vwf) {
  int blk = blockIdx.x, tid = threadIdx.x;
  if (blk < 960) {
    int o = blk / 10;
    int k = (blk - o * 10) * 256 + tid;
    int t = k >> 9, c = k & 511;
    const float* kwo = k_w + o * KCAT;
    float acc = (t == 2) ? kwo[c] : 0.f;
    if (t >= 1 && t <= 3) {
      const float* a = kwo + 512;
      const float* b = c3t + (size_t)((t - 1) * 512 + c) * 96;
      #pragma unroll
      for (int j = 0; j < 96; j += 4) {
        float4 bv = *(const float4*)(b + j);
        acc += a[j] * bv.x + a[j + 1] * bv.y + a[j + 2] * bv.z + a[j + 3] * bv.w;
      }
    }
    {
      const float* a = kwo + 608;
      const float* b = c5t + (size_t)(t * 512 + c) * 96;
      #pragma unroll
      for (int j = 0; j < 96; j += 4) {
        float4 bv = *(const float4*)(b + j);
        acc += a[j] * bv.x + a[j + 1] * bv.y + a[j + 2] * bv.z + a[j + 3] * bv.w;
      }
    }
    wefff[wfrag_idx(o, k)] = f2bf(acc);
  } else if (blk == 960) {
    if (tid < 96) {
      const float* kwo = k_w + tid * KCAT;
      float b = k_b[tid];
      for (int j = 0; j < 96; ++j)
        b += kwo[512 + j] * cn3_b[j] + kwo[608 + j] * cn5_b[j];
      beff[tid] = b;
    }
  } else if (blk < 1153) {              // q_w -> frag bf16 (96*512)
    int e = (blk - 961) * 256 + tid;
    int o = e >> 9, k = e & 511;
    qwf[wfrag_idx(o, k)] = f2bf(q_w[e]);
  } else {                              // v_w -> frag bf16 (96*1024)
    int e = (blk - 1153) * 256 + tid;
    int o = e >> 10, k = e & 1023;
    vwf[wfrag_idx(o, k)] = f2bf(v_w[e]);
  }
}

// ---------------------------------------------------------------------------
// Kernel 2: ALL projections in one launch.  grid (192, 8):
//   blockIdx.x/64 = mode (0: Q, 1: V, 2: K-conv), blockIdx.x%64 = 32-row tile.
// 4 waves per block, each owning a K-slice (K-conv: 640-wide slice, tap
// derived per 32-chunk).  Partials reduced via LDS in two 16-row passes.
// ---------------------------------------------------------------------------
__global__ __launch_bounds__(256, 2) void proj_all(
    const float* __restrict__ evo, const float* __restrict__ plm,
    const u16* __restrict__ qwf, const u16* __restrict__ vwf,
    const u16* __restrict__ wefff, const float* __restrict__ q_b,
    const float* __restrict__ v_b, const float* __restrict__ beff,
    u16* __restrict__ Qf, u16* __restrict__ Kf,
    u16* __restrict__ Vfr, u16* __restrict__ Vb) {
  __shared__ float Ls[4][16][97];
  int mode = blockIdx.x >> 6;
  int bx = blockIdx.x & 63;
  int bb = blockIdx.y;
  int tid = threadIdx.x;
  int wid = tid >> 6, lane = tid & 63, ln = lane & 15, kg = lane >> 4;

  f32x4 acc0[6], acc1[6];
  #pragma unroll
  for (int nt = 0; nt < 6; ++nt) {
    acc0[nt] = (f32x4){0.f, 0.f, 0.f, 0.f};
    acc1[nt] = (f32x4){0.f, 0.f, 0.f, 0.f};
  }

  if (mode == 0) {            // Q: A=evo[512], wave k-slice 128
    const float* x0 = evo + ((size_t)bb * LSEQ + bx * 32 + ln) * QIN + wid * 128;
    const float* x1 = x0 + (size_t)16 * QIN;
    #pragma unroll
    for (int kc = 0; kc < 4; ++kc) {
      int off = kc * 32 + kg * 8;
      s16x8 a0 = load8cvt(x0 + off);
      s16x8 a1 = load8cvt(x1 + off);
      const u16* wp = qwf + (size_t)(wid * 4 + kc) * 3072 + lane * 8;
      #pragma unroll
      for (int nt = 0; nt < 6; ++nt) {
        s16x8 bf = *(const s16x8*)&wp[(size_t)nt * 512];
        acc0[nt] = __builtin_amdgcn_mfma_f32_16x16x32_bf16(a0, bf, acc0[nt], 0, 0, 0);
        acc1[nt] = __builtin_amdgcn_mfma_f32_16x16x32_bf16(a1, bf, acc1[nt], 0, 0, 0);
      }
    }
  } else if (mode == 1) {     // V: A=plm[1024], wave k-slice 256
    const float* x0 = plm + ((size_t)bb * LSEQ + bx * 32 + ln) * VIN + wid * 256;
    const float* x1 = x0 + (size_t)16 * VIN;
    #pragma unroll 4
    for (int kc = 0; kc < 8; ++kc) {
      int off = kc * 32 + kg * 8;
      s16x8 a0 = load8cvt(x0 + off);
      s16x8 a1 = load8cvt(x1 + off);
      const u16* wp = vwf + (size_t)(wid * 8 + kc) * 3072 + lane * 8;
      #pragma unroll
      for (int nt = 0; nt < 6; ++nt) {
        s16x8 bf = *(const s16x8*)&wp[(size_t)nt * 512];
        acc0[nt] = __builtin_amdgcn_mfma_f32_16x16x32_bf16(a0, bf, acc0[nt], 0, 0, 0);
        acc1[nt] = __builtin_amdgcn_mfma_f32_16x16x32_bf16(a1, bf, acc1[nt], 0, 0, 0);
      }
    }
  } else {                    // K-conv: K=2560, wave k-slice 640
    int r0 = bx * 32 + ln;
    const float* xb = evo + (size_t)bb * LSEQ * QIN;
    #pragma unroll 4
    for (int kc = 0; kc < 20; ++kc) {
      int kglob = wid * 640 + kc * 32;
      int t = kglob >> 9;
      int c = (kglob & 511) + kg * 8;
      int s0 = r0 + t - 2, s1 = s0 + 16;
      s16x8 a0 = (s16x8){0, 0, 0, 0, 0, 0, 0, 0};
      s16x8 a1 = (s16x8){0, 0, 0, 0, 0, 0, 0, 0};
      if (s0 >= 0 && s0 < LSEQ) a0 = load8cvt(xb + (size_t)s0 * QIN + c);
      if (s1 < LSEQ) a1 = load8cvt(xb + (size_t)s1 * QIN + c);
      const u16* wp = wefff + (size_t)(wid * 20 + kc) * 3072 + lane * 8;
      #pragma unroll
      for (int nt = 0; nt < 6; ++nt) {
        s16x8 bf = *(const s16x8*)&wp[(size_t)nt * 512];
        acc0[nt] = __builtin_amdgcn_mfma_f32_16x16x32_bf16(a0, bf, acc0[nt], 0, 0, 0);
        acc1[nt] = __builtin_amdgcn_mfma_f32_16x16x32_bf16(a1, bf, acc1[nt], 0, 0, 0);
      }
    }
  }

  const float* bias = mode == 0 ? q_b : (mode == 1 ? v_b : beff);
  #pragma unroll
  for (int half = 0; half < 2; ++half) {
    if (half) __syncthreads();
    #pragma unroll
    for (int nt = 0; nt < 6; ++nt)
      #pragma unroll
      for (int r = 0; r < 4; ++r)
        Ls[wid][kg * 4 + r][nt * 16 + ln] = half ? acc1[nt][r] : acc0[nt][r];
    __syncthreads();
    if (tid < 192) {
      int r = tid / 12, cg = tid % 12;
      s16x8 ov;
      #pragma unroll
      for (int e = 0; e < 8; ++e) {
        int c = cg * 8 + e;
        float s = bias[c];
        #pragma unroll
        for (int w = 0; w < 4; ++w) s += Ls[w][r][c];
        ov[e] = (short)f2bf(s);
      }
      if (mode != 1) {
        size_t qt = (size_t)bb * 128 + bx * 2 + half;
        u16* dst = (mode == 0 ? Qf : Kf);
        *(s16x8*)&dst[((qt * 3 + (cg >> 2)) * 64 + (cg & 3) * 16 + r) * 8] = ov;
      } else {
        *(s16x8*)&Vb[((size_t)bb * LSEQ + bx * 32 + half * 16 + r) * 96 + cg * 8] = ov;
        // Vfrag: thread owns feature c, 8 consecutive keys
        int c = tid >> 1, kb = (tid & 1) + half * 2;
        s16x8 fv;
        #pragma unroll
        for (int e = 0; e < 8; ++e) {
          int lr = (tid & 1) * 8 + e;
          float s = bias[c];
          #pragma unroll
          for (int w = 0; w < 4; ++w) s += Ls[w][lr][c];
          fv[e] = (short)f2bf(s);
        }
        *(s16x8*)&Vfr[((((size_t)bb * 64 + bx) * 6 + (c >> 4)) * 64 +
                       kb * 16 + (c & 15)) * 8] = fv;
      }
    }
  }
}

// ---------------------------------------------------------------------------
// Kernel 3: flash attention + "+V", key-split across 4 waves, frag-layout
// operands, defer-max (skip O-rescale when tile max grows <= 8).
// 1D grid 1024, XCD-swizzled.
// ---------------------------------------------------------------------------
__global__ __launch_bounds__(256) void attn_kernel(
    const u16* __restrict__ Qf, const u16* __restrict__ Kf,
    const u16* __restrict__ Vfr, const u16* __restrict__ Vb,
    const int* __restrict__ seqlen, float* __restrict__ out) {
  __shared__ u16 Ps[4][16][40];       // per-wave P scratch
  __shared__ float Cacc[4][16][97];   // partial O
  __shared__ float Cml[4][16][2];     // partial m, l

  int bid = blockIdx.x;
  int swz = (bid & 7) * 128 + (bid >> 3);   // XCD x -> batch x
  int bb = swz >> 7, bx = swz & 127;
  int tid = threadIdx.x;
  int wid = tid >> 6, lane = tid & 63, ln = lane & 15, kg = lane >> 4;
  int n = seqlen[bb];
  int nkc = (n + 31) >> 5;

  size_t qt = (size_t)bb * 128 + bx;
  s16x8 aQ[3];
  #pragma unroll
  for (int kk = 0; kk < 3; ++kk)
    aQ[kk] = *(const s16x8*)&Qf[((qt * 3 + kk) * 64 + lane) * 8];

  float m[4], lsum[4];
  f32x4 acc[6];
  #pragma unroll
  for (int r = 0; r < 4; ++r) { m[r] = -1e30f; lsum[r] = 0.f; }
  #pragma unroll
  for (int nt = 0; nt < 6; ++nt) acc[nt] = (f32x4){0.f, 0.f, 0.f, 0.f};

  for (int kc = wid; kc < nkc; kc += 4) {
    int key0 = kc * 32;
    // ---- S = Q K^T ----
    const u16* kf0 = Kf + (((size_t)bb * 128 + kc * 2) * 3 * 64) * 8 + lane * 8;
    f32x4 s0 = (f32x4){0.f, 0.f, 0.f, 0.f};
    f32x4 s1 = (f32x4){0.f, 0.f, 0.f, 0.f};
    #pragma unroll
    for (int kk = 0; kk < 3; ++kk) {
      s16x8 b0 = *(const s16x8*)&kf0[(size_t)kk * 512];
      s0 = __builtin_amdgcn_mfma_f32_16x16x32_bf16(aQ[kk], b0, s0, 0, 0, 0);
      s16x8 b1 = *(const s16x8*)&kf0[(size_t)(3 + kk) * 512];
      s1 = __builtin_amdgcn_mfma_f32_16x16x32_bf16(aQ[kk], b1, s1, 0, 0, 0);
    }

    // ---- mask + scale, online softmax with defer-max ----
    bool v0 = (key0 + ln) < n;
    bool v1 = (key0 + 16 + ln) < n;
    float sv0[4], sv1[4], mx[4];
    #pragma unroll
    for (int r = 0; r < 4; ++r) {
      sv0[r] = v0 ? s0[r] * NORMS : -1e30f;
      sv1[r] = v1 ? s1[r] * NORMS : -1e30f;
      mx[r] = fmaxf(sv0[r], sv1[r]);
    }
    #pragma unroll
    for (int r = 0; r < 4; ++r) {
      mx[r] = fmaxf(mx[r], __shfl_xor(mx[r], 1, 16));
      mx[r] = fmaxf(mx[r], __shfl_xor(mx[r], 2, 16));
      mx[r] = fmaxf(mx[r], __shfl_xor(mx[r], 4, 16));
      mx[r] = fmaxf(mx[r], __shfl_xor(mx[r], 8, 16));
    }
    float p0[4], p1[4], rs[4];
    bool defer = __all((mx[0] <= m[0] + 8.f) && (mx[1] <= m[1] + 8.f) &&
                       (mx[2] <= m[2] + 8.f) && (mx[3] <= m[3] + 8.f));
    if (defer) {
      #pragma unroll
      for (int r = 0; r < 4; ++r) {
        p0[r] = __expf(sv0[r] - m[r]);
        p1[r] = __expf(sv1[r] - m[r]);
        rs[r] = p0[r] + p1[r];
      }
      #pragma unroll
      for (int r = 0; r < 4; ++r) {
        rs[r] += __shfl_xor(rs[r], 1, 16);
        rs[r] += __shfl_xor(rs[r], 2, 16);
        rs[r] += __shfl_xor(rs[r], 4, 16);
        rs[r] += __shfl_xor(rs[r], 8, 16);
        lsum[r] += rs[r];
      }
    } else {
      float fac[4];
      #pragma unroll
      for (int r = 0; r < 4; ++r) {
        float mn = fmaxf(m[r], mx[r]);
        fac[r] = __expf(m[r] - mn);
        p0[r] = __expf(sv0[r] - mn);
        p1[r] = __expf(sv1[r] - mn);
        rs[r] = p0[r] + p1[r];
        m[r] = mn;
      }
      #pragma unroll
      for (int r = 0; r < 4; ++r) {
        rs[r] += __shfl_xor(rs[r], 1, 16);
        rs[r] += __shfl_xor(rs[r], 2, 16);
        rs[r] += __shfl_xor(rs[r], 4, 16);
        rs[r] += __shfl_xor(rs[r], 8, 16);
        lsum[r] = lsum[r] * fac[r] + rs[r];
      }
      #pragma unroll
      for (int nt = 0; nt < 6; ++nt)
        #pragma unroll
        for (int r = 0; r < 4; ++r) acc[nt][r] *= fac[r];
    }

    // ---- P (D-layout) -> per-wave LDS -> A-frag (bf16) ----
    u16* Pw = &Ps[wid][0][0];
    #pragma unroll
    for (int r = 0; r < 4; ++r) {
      Pw[(kg * 4 + r) * 40 + ln] = f2bf(p0[r]);
      Pw[(kg * 4 + r) * 40 + 16 + ln] = f2bf(p1[r]);
    }
    s16x8 pa = *(const s16x8*)&Pw[ln * 40 + kg * 8];

    // ---- acc += P @ V ----
    const u16* vf = Vfr + (((size_t)bb * 64 + kc) * 6 * 64) * 8 + lane * 8;
    #pragma unroll
    for (int nt = 0; nt < 6; ++nt) {
      s16x8 bv = *(const s16x8*)&vf[(size_t)nt * 512];
      acc[nt] = __builtin_amdgcn_mfma_f32_16x16x32_bf16(pa, bv, acc[nt], 0, 0, 0);
    }
  }

  // ---- write partials ----
  #pragma unroll
  for (int nt = 0; nt < 6; ++nt)
    #pragma unroll
    for (int r = 0; r < 4; ++r)
      Cacc[wid][kg * 4 + r][nt * 16 + ln] = acc[nt][r];
  if (ln == 0) {
    #pragma unroll
    for (int r = 0; r < 4; ++r) {
      Cml[wid][kg * 4 + r][0] = m[r];
      Cml[wid][kg * 4 + r][1] = lsum[r];
    }
  }
  __syncthreads();

  // ---- combine 4 key-split partials + "+V" ----
  size_t obase = ((size_t)bb * LSEQ + bx * 16) * 96;
  for (int i = tid; i < 1536; i += 256) {
    int row = i / 96;
    float mg = -1e30f;
    #pragma unroll
    for (int w = 0; w < 4; ++w) mg = fmaxf(mg, Cml[w][row][0]);
    float lg = 0.f, av = 0.f;
    #pragma unroll
    for (int w = 0; w < 4; ++w) {
      float e = __expf(Cml[w][row][0] - mg);
      lg += Cml[w][row][1] * e;
      av += Cacc[w][row][i - row * 96] * e;
    }
    out[obase + i] = av / lg + bf2f(Vb[obase + i]);
  }
}

// ---------------------------------------------------------------------------
extern "C" void kernel_launch(void* const* d_in, const int* in_sizes, int n_in,
                              void* d_out, int out_size, void* d_ws,
                              size_t ws_size, hipStream_t stream) {
  const float* plm   = (const float*)d_in[0];
  const float* evo   = (const float*)d_in[1];
  const int* seqlen  = (const int*)d_in[2];
  const float* q_w   = (const float*)d_in[3];
  const float* q_b   = (const float*)d_in[4];
  const float* k_w   = (const float*)d_in[5];
  const float* k_b   = (const float*)d_in[6];
  const float* v_w   = (const float*)d_in[7];
  const float* v_b   = (const float*)d_in[8];
  const float* cn3_w = (const float*)d_in[9];
  const float* cn3_b = (const float*)d_in[10];
  const float* cn5_w = (const float*)d_in[11];
  const float* cn5_b = (const float*)d_in[12];

  char* ws = (char*)d_ws;
  u16* wefff  = (u16*)(ws + 0);           // 491520
  float* beff = (float*)(ws + 491520);    // 512
  u16* qwf    = (u16*)(ws + 492032);      // 98304
  u16* vwf    = (u16*)(ws + 590336);      // 196608
  float* c3t  = (float*)(ws + 786944);    // 589824
  float* c5t  = (float*)(ws + 1376768);   // 983040
  u16* Qf     = (u16*)(ws + 2359808);     // 3145728 (Q frag layout)
  u16* Kf     = (u16*)(ws + 5505536);     // 3145728 (K frag layout)
  u16* Vfr    = (u16*)(ws + 8651264);     // 3145728 (V frag layout)
  u16* Vb     = (u16*)(ws + 11796992);    // 3145728 (V row-major bf16)
  float* out  = (float*)d_out;

  prep_transpose<<<1536, 256, 0, stream>>>(cn3_w, cn5_w, c3t, c5t);
  prep_fold<<<1537, 256, 0, stream>>>(q_w, k_w, k_b, v_w, c3t, cn3_b,
                                      c5t, cn5_b, wefff, beff, qwf, vwf);
  proj_all<<<dim3(192, 8), 256, 0, stream>>>(evo, plm, qwf, vwf, wefff,
                                             q_b, v_b, beff, Qf, Kf, Vfr, Vb);
  attn_kernel<<<1024, 256, 0, stream>>>(Qf, Kf, Vfr, Vb, seqlen, out);
}

// Round 7
// 145.354 us; speedup vs baseline: 1.0543x; 1.0543x over previous
//
#include <hip/hip_runtime.h>

typedef unsigned short u16;
typedef unsigned int u32;
typedef float f32x4 __attribute__((ext_vector_type(4)));
typedef short s16x8 __attribute__((ext_vector_type(8)));

#define LSEQ 2048
#define QIN 512
#define VIN 1024
#define KCAT 704
#define KEFF 2560
#define NORMS 0.10206207261596575f  // 1/sqrt(96)

__device__ __forceinline__ u16 f2bf(float f) {
  u32 u = __float_as_uint(f);
  u = (u + 0x7fffu + ((u >> 16) & 1u)) >> 16;  // RNE
  return (u16)u;
}
__device__ __forceinline__ float bf2f(u16 v) {
  return __uint_as_float(((u32)v) << 16);
}

__device__ __forceinline__ s16x8 load8cvt(const float* __restrict__ p) {
  float4 a = *(const float4*)p;
  float4 b = *(const float4*)(p + 4);
  s16x8 r;
  r[0] = (short)f2bf(a.x); r[1] = (short)f2bf(a.y);
  r[2] = (short)f2bf(a.z); r[3] = (short)f2bf(a.w);
  r[4] = (short)f2bf(b.x); r[5] = (short)f2bf(b.y);
  r[6] = (short)f2bf(b.z); r[7] = (short)f2bf(b.w);
  return r;
}

__device__ __forceinline__ s16x8 cvt2x4(float4 a, float4 b) {
  s16x8 r;
  r[0] = (short)f2bf(a.x); r[1] = (short)f2bf(a.y);
  r[2] = (short)f2bf(a.z); r[3] = (short)f2bf(a.w);
  r[4] = (short)f2bf(b.x); r[5] = (short)f2bf(b.y);
  r[6] = (short)f2bf(b.z); r[7] = (short)f2bf(b.w);
  return r;
}

// Fragment-linear index for a weight matrix W[N=96][K]:
// element W[o][k] -> ((kc*6 + nt)*64 + kg*16 + ln)*8 + j
__device__ __forceinline__ size_t wfrag_idx(int o, int k) {
  int kc = k >> 5, kg = (k >> 3) & 3, j = k & 7;
  int nt = o >> 4, ln = o & 15;
  return ((size_t)(kc * 6 + nt) * 64 + kg * 16 + ln) * 8 + j;
}

// ---------------------------------------------------------------------------
// Kernel 1 (prep1): conv-weight transposes (c3t[t][c][j], c5t[t][c][j]),
// q_w/v_w -> frag bf16, k_w conv-slices -> tiny frags kw3f/kw5f, b_eff.
// blocks: [0,576) c3t, [576,1536) c5t, [1536,1728) qwf, [1728,2112) vwf,
//         [2112,2184) kw3f/kw5f, 2184 b_eff.
// ---------------------------------------------------------------------------
__global__ __launch_bounds__(256) void prep1(
    const float* __restrict__ q_w, const float* __restrict__ k_w,
    const float* __restrict__ k_b, const float* __restrict__ v_w,
    const float* __restrict__ cn3_w, const float* __restrict__ cn3_b,
    const float* __restrict__ cn5_w, const float* __restrict__ cn5_b,
    float* __restrict__ c3t, float* __restrict__ c5t,
    u16* __restrict__ qwf, u16* __restrict__ vwf,
    u16* __restrict__ kw3f, u16* __restrict__ kw5f,
    float* __restrict__ beff) {
  int blk = blockIdx.x, tid = threadIdx.x;
  if (blk < 576) {                       // c3t: 147456
    int idx = blk * 256 + tid;
    int t = idx / (512 * 96);
    int rem = idx - t * 512 * 96;
    int c = rem / 96, j = rem - c * 96;
    c3t[idx] = cn3_w[(j * 512 + c) * 3 + t];
  } else if (blk < 1536) {               // c5t: 245760
    int idx = (blk - 576) * 256 + tid;
    int t = idx / (512 * 96);
    int rem = idx - t * 512 * 96;
    int c = rem / 96, j = rem - c * 96;
    c5t[idx] = cn5_w[(j * 512 + c) * 5 + t];
  } else if (blk < 1728) {               // qwf: 49152
    int e = (blk - 1536) * 256 + tid;
    int o = e >> 9, k = e & 511;
    qwf[wfrag_idx(o, k)] = f2bf(q_w[e]);
  } else if (blk < 2112) {               // vwf: 98304
    int e = (blk - 1728) * 256 + tid;
    int o = e >> 10, k = e & 1023;
    vwf[wfrag_idx(o, k)] = f2bf(v_w[e]);
  } else if (blk < 2184) {               // kw3f + kw5f: 2*9216
    int e = (blk - 2112) * 256 + tid;
    int half = e / 9216;
    int i = e - half * 9216;
    int o = i / 96, j = i - o * 96;
    float v = k_w[o * KCAT + (half ? 608 : 512) + j];
    size_t di = ((size_t)((j >> 5) * 6 + (o >> 4)) * 64 +
                 ((j >> 3) & 3) * 16 + (o & 15)) * 8 + (j & 7);
    (half ? kw5f : kw3f)[di] = f2bf(v);
  } else {                               // b_eff
    if (tid < 96) {
      const float* kwo = k_w + tid * KCAT;
      float b = k_b[tid];
      for (int j = 0; j < 96; ++j)
        b += kwo[512 + j] * cn3_b[j] + kwo[608 + j] * cn5_b[j];
      beff[tid] = b;
    }
  }
}

// ---------------------------------------------------------------------------
// Kernel 2 (prep2): W_eff fold as a GEMM.  W_eff^T[k][o] =
//   c5t[k][:]·kw5 + (512<=k<2048 ? c3t[k-512][:]·kw3 : 0) + (t==2 ? k_w[o][c] : 0)
// M=2560 k-rows, N=96, K=96.  grid 40 blocks x 4 waves x 16 rows.
// Output in wefff frag layout.
// ---------------------------------------------------------------------------
__global__ __launch_bounds__(256) void prep2(
    const float* __restrict__ c3t, const float* __restrict__ c5t,
    const u16* __restrict__ kw3f, const u16* __restrict__ kw5f,
    const float* __restrict__ k_w, u16* __restrict__ wefff) {
  __shared__ float Ls[4][16][100];
  int blk = blockIdx.x, tid = threadIdx.x;
  int wid = tid >> 6, lane = tid & 63, ln = lane & 15, kg = lane >> 4;
  int k = blk * 64 + wid * 16 + ln;
  bool c3ok = (k >= 512) && (k < 2048);
  const float* a5 = c5t + (size_t)k * 96;
  const float* a3 = c3t + (size_t)(c3ok ? k - 512 : 0) * 96;
  f32x4 acc[6];
  #pragma unroll
  for (int nt = 0; nt < 6; ++nt) acc[nt] = (f32x4){0.f, 0.f, 0.f, 0.f};
  #pragma unroll
  for (int jc = 0; jc < 3; ++jc) {
    s16x8 aa5 = load8cvt(a5 + jc * 32 + kg * 8);
    s16x8 aa3 = (s16x8){0, 0, 0, 0, 0, 0, 0, 0};
    if (c3ok) aa3 = load8cvt(a3 + jc * 32 + kg * 8);
    const u16* b5 = kw5f + (size_t)jc * 3072 + lane * 8;
    const u16* b3 = kw3f + (size_t)jc * 3072 + lane * 8;
    #pragma unroll
    for (int nt = 0; nt < 6; ++nt) {
      acc[nt] = __builtin_amdgcn_mfma_f32_16x16x32_bf16(
          aa5, *(const s16x8*)&b5[nt * 512], acc[nt], 0, 0, 0);
      acc[nt] = __builtin_amdgcn_mfma_f32_16x16x32_bf16(
          aa3, *(const s16x8*)&b3[nt * 512], acc[nt], 0, 0, 0);
    }
  }
  #pragma unroll
  for (int nt = 0; nt < 6; ++nt)
    #pragma unroll
    for (int r = 0; r < 4; ++r)
      Ls[wid][kg * 4 + r][nt * 16 + ln] = acc[nt][r];
  asm volatile("s_waitcnt lgkmcnt(0)" ::: "memory");
  #pragma unroll
  for (int sl = 0; sl < 3; ++sl) {
    int slot = sl * 64 + lane;
    int o = slot >> 1, rc = slot & 1;
    int k0 = blk * 64 + wid * 16 + rc * 8;
    int t = k0 >> 9, cbase = k0 & 511;
    s16x8 ov;
    #pragma unroll
    for (int e = 0; e < 8; ++e) {
      float v = Ls[wid][rc * 8 + e][o];
      if (t == 2) v += k_w[o * KCAT + cbase + e];
      ov[e] = (short)f2bf(v);
    }
    *(s16x8*)&wefff[((size_t)((k0 >> 5) * 6 + (o >> 4)) * 64 +
                     ((k0 >> 3) & 3) * 16 + (o & 15)) * 8] = ov;
  }
}

// ---------------------------------------------------------------------------
// Kernel 3: Q + K-conv fused, LDS-staged double-buffered.
// grid (32,8): 64 rows/block, 4 waves x 16 rows.  Stage evo tile with 2-row
// halo each side (68 rows x 64 k) as bf16; all 5 taps + Q read the same tile.
// ---------------------------------------------------------------------------
__global__ __launch_bounds__(256) void qk_proj(
    const float* __restrict__ evo, const u16* __restrict__ qwf,
    const u16* __restrict__ wefff, const float* __restrict__ q_b,
    const float* __restrict__ beff, u16* __restrict__ Qf,
    u16* __restrict__ Kf) {
  __shared__ u16 At[2 * 68 * 72];
  __shared__ float Ls[4][16][100];
  int bx = blockIdx.x, bb = blockIdx.y;
  int tid = threadIdx.x;
  int wid = tid >> 6, lane = tid & 63, ln = lane & 15, kg = lane >> 4;
  int r0 = bx * 64;
  const float* xb = evo + (size_t)bb * LSEQ * QIN;

  int srow = tid >> 2, spart = tid & 3;
  bool halo = tid < 16;
  int hrow = 64 + (tid >> 2);

  float4 ra0, ra1, ra2, ra3, rb0, rb1, rb2, rb3;
  auto LOADS = [&](int s) {
    int g = r0 - 2 + srow;
    if (g >= 0 && g < LSEQ) {
      const float* p = xb + (size_t)g * QIN + s * 64 + spart * 16;
      ra0 = *(const float4*)p;       ra1 = *(const float4*)(p + 4);
      ra2 = *(const float4*)(p + 8); ra3 = *(const float4*)(p + 12);
    } else {
      ra0 = ra1 = ra2 = ra3 = make_float4(0.f, 0.f, 0.f, 0.f);
    }
    if (halo) {
      int g2 = r0 - 2 + hrow;
      if (g2 < LSEQ) {
        const float* p = xb + (size_t)g2 * QIN + s * 64 + spart * 16;
        rb0 = *(const float4*)p;       rb1 = *(const float4*)(p + 4);
        rb2 = *(const float4*)(p + 8); rb3 = *(const float4*)(p + 12);
      } else {
        rb0 = rb1 = rb2 = rb3 = make_float4(0.f, 0.f, 0.f, 0.f);
      }
    }
  };
  auto WRITES = [&](int buf) {
    u16* d = &At[(buf * 68 + srow) * 72 + spart * 16];
    *(s16x8*)d = cvt2x4(ra0, ra1);
    *(s16x8*)(d + 8) = cvt2x4(ra2, ra3);
    if (halo) {
      u16* d2 = &At[(buf * 68 + hrow) * 72 + spart * 16];
      *(s16x8*)d2 = cvt2x4(rb0, rb1);
      *(s16x8*)(d2 + 8) = cvt2x4(rb2, rb3);
    }
  };

  f32x4 accQ[6], accK[6];
  #pragma unroll
  for (int nt = 0; nt < 6; ++nt) {
    accQ[nt] = (f32x4){0.f, 0.f, 0.f, 0.f};
    accK[nt] = (f32x4){0.f, 0.f, 0.f, 0.f};
  }

  LOADS(0);
  WRITES(0);
  __syncthreads();
  int cur = 0;
  for (int s = 0; s < 8; ++s) {
    if (s < 7) LOADS(s + 1);
    #pragma unroll
    for (int cc = 0; cc < 2; ++cc) {
      int colb = cc * 32 + kg * 8;
      int kcg = s * 2 + cc;
      const u16* arow = &At[(cur * 68 + wid * 16 + ln) * 72 + colb];
      s16x8 aQ = *(const s16x8*)&arow[2 * 72];
      const u16* bq = qwf + (size_t)kcg * 3072 + lane * 8;
      #pragma unroll
      for (int nt = 0; nt < 6; ++nt)
        accQ[nt] = __builtin_amdgcn_mfma_f32_16x16x32_bf16(
            aQ, *(const s16x8*)&bq[nt * 512], accQ[nt], 0, 0, 0);
      #pragma unroll
      for (int t = 0; t < 5; ++t) {
        s16x8 aK = *(const s16x8*)&arow[t * 72];
        const u16* bk = wefff + (size_t)(t * 16 + kcg) * 3072 + lane * 8;
        #pragma unroll
        for (int nt = 0; nt < 6; ++nt)
          accK[nt] = __builtin_amdgcn_mfma_f32_16x16x32_bf16(
              aK, *(const s16x8*)&bk[nt * 512], accK[nt], 0, 0, 0);
      }
    }
    if (s < 7) {
      WRITES(cur ^ 1);
      __syncthreads();
      cur ^= 1;
    }
  }

  // epilogue: per-wave transpose via Ls[wid], then frag stores
  size_t qt = (size_t)bb * 128 + bx * 4 + wid;
  #pragma unroll
  for (int nt = 0; nt < 6; ++nt)
    #pragma unroll
    for (int r = 0; r < 4; ++r)
      Ls[wid][kg * 4 + r][nt * 16 + ln] = accQ[nt][r];
  asm volatile("s_waitcnt lgkmcnt(0)" ::: "memory");
  #pragma unroll
  for (int sl = 0; sl < 3; ++sl) {
    int slot = sl * 64 + lane;
    int r = slot / 12, cg = slot % 12;
    s16x8 ov;
    #pragma unroll
    for (int e = 0; e < 8; ++e) {
      int c = cg * 8 + e;
      ov[e] = (short)f2bf(Ls[wid][r][c] + q_b[c]);
    }
    *(s16x8*)&Qf[((qt * 3 + (cg >> 2)) * 64 + (cg & 3) * 16 + r) * 8] = ov;
  }
  asm volatile("s_waitcnt lgkmcnt(0) vmcnt(0)" ::: "memory");
  #pragma unroll
  for (int nt = 0; nt < 6; ++nt)
    #pragma unroll
    for (int r = 0; r < 4; ++r)
      Ls[wid][kg * 4 + r][nt * 16 + ln] = accK[nt][r];
  asm volatile("s_waitcnt lgkmcnt(0)" ::: "memory");
  #pragma unroll
  for (int sl = 0; sl < 3; ++sl) {
    int slot = sl * 64 + lane;
    int r = slot / 12, cg = slot % 12;
    s16x8 ov;
    #pragma unroll
    for (int e = 0; e < 8; ++e) {
      int c = cg * 8 + e;
      ov[e] = (short)f2bf(Ls[wid][r][c] + beff[c]);
    }
    *(s16x8*)&Kf[((qt * 3 + (cg >> 2)) * 64 + (cg & 3) * 16 + r) * 8] = ov;
  }
}

// ---------------------------------------------------------------------------
// Kernel 4: V projection, LDS-staged double-buffered.  grid (32,8), 64
// rows/block, 4 waves x 16 rows, K=1024 in 16 steps of 64.
// Writes Vfr (frag) + Vb (row-major bf16).
// ---------------------------------------------------------------------------
__global__ __launch_bounds__(256) void v_proj(
    const float* __restrict__ plm, const u16* __restrict__ vwf,
    const float* __restrict__ v_b, u16* __restrict__ Vfr,
    u16* __restrict__ Vb) {
  __shared__ u16 At[2 * 64 * 72];
  __shared__ float Ls[4][16][100];
  int bx = blockIdx.x, bb = blockIdx.y;
  int tid = threadIdx.x;
  int wid = tid >> 6, lane = tid & 63, ln = lane & 15, kg = lane >> 4;
  const float* xb = plm + ((size_t)bb * LSEQ + bx * 64) * VIN;

  int srow = tid >> 2, spart = tid & 3;
  float4 ra0, ra1, ra2, ra3;
  auto LOADS = [&](int s) {
    const float* p = xb + (size_t)srow * VIN + s * 64 + spart * 16;
    ra0 = *(const float4*)p;       ra1 = *(const float4*)(p + 4);
    ra2 = *(const float4*)(p + 8); ra3 = *(const float4*)(p + 12);
  };
  auto WRITES = [&](int buf) {
    u16* d = &At[(buf * 64 + srow) * 72 + spart * 16];
    *(s16x8*)d = cvt2x4(ra0, ra1);
    *(s16x8*)(d + 8) = cvt2x4(ra2, ra3);
  };

  f32x4 acc[6];
  #pragma unroll
  for (int nt = 0; nt < 6; ++nt) acc[nt] = (f32x4){0.f, 0.f, 0.f, 0.f};

  LOADS(0);
  WRITES(0);
  __syncthreads();
  int cur = 0;
  for (int s = 0; s < 16; ++s) {
    if (s < 15) LOADS(s + 1);
    #pragma unroll
    for (int cc = 0; cc < 2; ++cc) {
      int colb = cc * 32 + kg * 8;
      int kcg = s * 2 + cc;
      s16x8 a = *(const s16x8*)&At[(cur * 64 + wid * 16 + ln) * 72 + colb];
      const u16* bv = vwf + (size_t)kcg * 3072 + lane * 8;
      #pragma unroll
      for (int nt = 0; nt < 6; ++nt)
        acc[nt] = __builtin_amdgcn_mfma_f32_16x16x32_bf16(
            a, *(const s16x8*)&bv[nt * 512], acc[nt], 0, 0, 0);
    }
    if (s < 15) {
      WRITES(cur ^ 1);
      __syncthreads();
      cur ^= 1;
    }
  }

  #pragma unroll
  for (int nt = 0; nt < 6; ++nt)
    #pragma unroll
    for (int r = 0; r < 4; ++r)
      Ls[wid][kg * 4 + r][nt * 16 + ln] = acc[nt][r];
  asm volatile("s_waitcnt lgkmcnt(0)" ::: "memory");
  // Vb row-major
  #pragma unroll
  for (int sl = 0; sl < 3; ++sl) {
    int slot = sl * 64 + lane;
    int r = slot / 12, cg = slot % 12;
    s16x8 ov;
    #pragma unroll
    for (int e = 0; e < 8; ++e) {
      int c = cg * 8 + e;
      ov[e] = (short)f2bf(Ls[wid][r][c] + v_b[c]);
    }
    *(s16x8*)&Vb[((size_t)bb * LSEQ + bx * 64 + wid * 16 + r) * 96 + cg * 8] = ov;
  }
  // Vfr: thread owns feature c, 8 consecutive keys
  #pragma unroll
  for (int sl = 0; sl < 3; ++sl) {
    int slot = sl * 64 + lane;
    int c = slot >> 1, rc = slot & 1;
    int key0 = bx * 64 + wid * 16 + rc * 8;
    s16x8 fv;
    #pragma unroll
    for (int e = 0; e < 8; ++e)
      fv[e] = (short)f2bf(Ls[wid][rc * 8 + e][c] + v_b[c]);
    *(s16x8*)&Vfr[(((size_t)bb * 64 + (key0 >> 5)) * 6 + (c >> 4)) * 512 +
                  (((key0 >> 3) & 3) * 16 + (c & 15)) * 8] = fv;
  }
}

// ---------------------------------------------------------------------------
// Kernel 5: flash attention + "+V" (unchanged from round 6).
// ---------------------------------------------------------------------------
__global__ __launch_bounds__(256) void attn_kernel(
    const u16* __restrict__ Qf, const u16* __restrict__ Kf,
    const u16* __restrict__ Vfr, const u16* __restrict__ Vb,
    const int* __restrict__ seqlen, float* __restrict__ out) {
  __shared__ u16 Ps[4][16][40];
  __shared__ float Cacc[4][16][97];
  __shared__ float Cml[4][16][2];

  int bid = blockIdx.x;
  int swz = (bid & 7) * 128 + (bid >> 3);
  int bb = swz >> 7, bx = swz & 127;
  int tid = threadIdx.x;
  int wid = tid >> 6, lane = tid & 63, ln = lane & 15, kg = lane >> 4;
  int n = seqlen[bb];
  int nkc = (n + 31) >> 5;

  size_t qt = (size_t)bb * 128 + bx;
  s16x8 aQ[3];
  #pragma unroll
  for (int kk = 0; kk < 3; ++kk)
    aQ[kk] = *(const s16x8*)&Qf[((qt * 3 + kk) * 64 + lane) * 8];

  float m[4], lsum[4];
  f32x4 acc[6];
  #pragma unroll
  for (int r = 0; r < 4; ++r) { m[r] = -1e30f; lsum[r] = 0.f; }
  #pragma unroll
  for (int nt = 0; nt < 6; ++nt) acc[nt] = (f32x4){0.f, 0.f, 0.f, 0.f};

  for (int kc = wid; kc < nkc; kc += 4) {
    int key0 = kc * 32;
    const u16* kf0 = Kf + (((size_t)bb * 128 + kc * 2) * 3 * 64) * 8 + lane * 8;
    f32x4 s0 = (f32x4){0.f, 0.f, 0.f, 0.f};
    f32x4 s1 = (f32x4){0.f, 0.f, 0.f, 0.f};
    #pragma unroll
    for (int kk = 0; kk < 3; ++kk) {
      s16x8 b0 = *(const s16x8*)&kf0[(size_t)kk * 512];
      s0 = __builtin_amdgcn_mfma_f32_16x16x32_bf16(aQ[kk], b0, s0, 0, 0, 0);
      s16x8 b1 = *(const s16x8*)&kf0[(size_t)(3 + kk) * 512];
      s1 = __builtin_amdgcn_mfma_f32_16x16x32_bf16(aQ[kk], b1, s1, 0, 0, 0);
    }

    bool v0 = (key0 + ln) < n;
    bool v1 = (key0 + 16 + ln) < n;
    float sv0[4], sv1[4], mx[4];
    #pragma unroll
    for (int r = 0; r < 4; ++r) {
      sv0[r] = v0 ? s0[r] * NORMS : -1e30f;
      sv1[r] = v1 ? s1[r] * NORMS : -1e30f;
      mx[r] = fmaxf(sv0[r], sv1[r]);
    }
    #pragma unroll
    for (int r = 0; r < 4; ++r) {
      mx[r] = fmaxf(mx[r], __shfl_xor(mx[r], 1, 16));
      mx[r] = fmaxf(mx[r], __shfl_xor(mx[r], 2, 16));
      mx[r] = fmaxf(mx[r], __shfl_xor(mx[r], 4, 16));
      mx[r] = fmaxf(mx[r], __shfl_xor(mx[r], 8, 16));
    }
    float p0[4], p1[4], rs[4];
    bool defer = __all((mx[0] <= m[0] + 8.f) && (mx[1] <= m[1] + 8.f) &&
                       (mx[2] <= m[2] + 8.f) && (mx[3] <= m[3] + 8.f));
    if (defer) {
      #pragma unroll
      for (int r = 0; r < 4; ++r) {
        p0[r] = __expf(sv0[r] - m[r]);
        p1[r] = __expf(sv1[r] - m[r]);
        rs[r] = p0[r] + p1[r];
      }
      #pragma unroll
      for (int r = 0; r < 4; ++r) {
        rs[r] += __shfl_xor(rs[r], 1, 16);
        rs[r] += __shfl_xor(rs[r], 2, 16);
        rs[r] += __shfl_xor(rs[r], 4, 16);
        rs[r] += __shfl_xor(rs[r], 8, 16);
        lsum[r] += rs[r];
      }
    } else {
      float fac[4];
      #pragma unroll
      for (int r = 0; r < 4; ++r) {
        float mn = fmaxf(m[r], mx[r]);
        fac[r] = __expf(m[r] - mn);
        p0[r] = __expf(sv0[r] - mn);
        p1[r] = __expf(sv1[r] - mn);
        rs[r] = p0[r] + p1[r];
        m[r] = mn;
      }
      #pragma unroll
      for (int r = 0; r < 4; ++r) {
        rs[r] += __shfl_xor(rs[r], 1, 16);
        rs[r] += __shfl_xor(rs[r], 2, 16);
        rs[r] += __shfl_xor(rs[r], 4, 16);
        rs[r] += __shfl_xor(rs[r], 8, 16);
        lsum[r] = lsum[r] * fac[r] + rs[r];
      }
      #pragma unroll
      for (int nt = 0; nt < 6; ++nt)
        #pragma unroll
        for (int r = 0; r < 4; ++r) acc[nt][r] *= fac[r];
    }

    u16* Pw = &Ps[wid][0][0];
    #pragma unroll
    for (int r = 0; r < 4; ++r) {
      Pw[(kg * 4 + r) * 40 + ln] = f2bf(p0[r]);
      Pw[(kg * 4 + r) * 40 + 16 + ln] = f2bf(p1[r]);
    }
    s16x8 pa = *(const s16x8*)&Pw[ln * 40 + kg * 8];

    const u16* vf = Vfr + (((size_t)bb * 64 + kc) * 6 * 64) * 8 + lane * 8;
    #pragma unroll
    for (int nt = 0; nt < 6; ++nt) {
      s16x8 bv = *(const s16x8*)&vf[(size_t)nt * 512];
      acc[nt] = __builtin_amdgcn_mfma_f32_16x16x32_bf16(pa, bv, acc[nt], 0, 0, 0);
    }
  }

  #pragma unroll
  for (int nt = 0; nt < 6; ++nt)
    #pragma unroll
    for (int r = 0; r < 4; ++r)
      Cacc[wid][kg * 4 + r][nt * 16 + ln] = acc[nt][r];
  if (ln == 0) {
    #pragma unroll
    for (int r = 0; r < 4; ++r) {
      Cml[wid][kg * 4 + r][0] = m[r];
      Cml[wid][kg * 4 + r][1] = lsum[r];
    }
  }
  __syncthreads();

  size_t obase = ((size_t)bb * LSEQ + bx * 16) * 96;
  for (int i = tid; i < 1536; i += 256) {
    int row = i / 96;
    float mg = -1e30f;
    #pragma unroll
    for (int w = 0; w < 4; ++w) mg = fmaxf(mg, Cml[w][row][0]);
    float lg = 0.f, av = 0.f;
    #pragma unroll
    for (int w = 0; w < 4; ++w) {
      float e = __expf(Cml[w][row][0] - mg);
      lg += Cml[w][row][1] * e;
      av += Cacc[w][row][i - row * 96] * e;
    }
    out[obase + i] = av / lg + bf2f(Vb[obase + i]);
  }
}

// ---------------------------------------------------------------------------
extern "C" void kernel_launch(void* const* d_in, const int* in_sizes, int n_in,
                              void* d_out, int out_size, void* d_ws,
                              size_t ws_size, hipStream_t stream) {
  const float* plm   = (const float*)d_in[0];
  const float* evo   = (const float*)d_in[1];
  const int* seqlen  = (const int*)d_in[2];
  const float* q_w   = (const float*)d_in[3];
  const float* q_b   = (const float*)d_in[4];
  const float* k_w   = (const float*)d_in[5];
  const float* k_b   = (const float*)d_in[6];
  const float* v_w   = (const float*)d_in[7];
  const float* v_b   = (const float*)d_in[8];
  const float* cn3_w = (const float*)d_in[9];
  const float* cn3_b = (const float*)d_in[10];
  const float* cn5_w = (const float*)d_in[11];
  const float* cn5_b = (const float*)d_in[12];

  char* ws = (char*)d_ws;
  u16* wefff  = (u16*)(ws + 0);           // 491520
  float* beff = (float*)(ws + 491520);    // 512
  u16* qwf    = (u16*)(ws + 492032);      // 98304
  u16* vwf    = (u16*)(ws + 590336);      // 196608
  float* c3t  = (float*)(ws + 786944);    // 589824
  float* c5t  = (float*)(ws + 1376768);   // 983040
  u16* kw3f   = (u16*)(ws + 2359808);     // 18432
  u16* kw5f   = (u16*)(ws + 2378240);     // 18432
  u16* Qf     = (u16*)(ws + 2396672);     // 3145728
  u16* Kf     = (u16*)(ws + 5542400);     // 3145728
  u16* Vfr    = (u16*)(ws + 8688128);     // 3145728
  u16* Vb     = (u16*)(ws + 11833856);    // 3145728
  float* out  = (float*)d_out;

  prep1<<<2185, 256, 0, stream>>>(q_w, k_w, k_b, v_w, cn3_w, cn3_b, cn5_w,
                                  cn5_b, c3t, c5t, qwf, vwf, kw3f, kw5f, beff);
  prep2<<<40, 256, 0, stream>>>(c3t, c5t, kw3f, kw5f, k_w, wefff);
  dim3 g(32, 8);
  qk_proj<<<g, 256, 0, stream>>>(evo, qwf, wefff, q_b, beff, Qf, Kf);
  v_proj<<<g, 256, 0, stream>>>(plm, vwf, v_b, Vfr, Vb);
  attn_kernel<<<1024, 256, 0, stream>>>(Qf, Kf, Vfr, Vb, seqlen, out);
}

// Round 8
// 105.326 us; speedup vs baseline: 1.4549x; 1.3800x over previous
//
#include <hip/hip_runtime.h>

typedef unsigned short u16;
typedef unsigned int u32;
typedef float f32x4 __attribute__((ext_vector_type(4)));
typedef short s16x8 __attribute__((ext_vector_type(8)));

#define LSEQ 2048
#define QIN 512
#define VIN 1024
#define KCAT 704
#define KEFF 2560
#define NORMS 0.10206207261596575f  // 1/sqrt(96)

__device__ __forceinline__ u16 f2bf(float f) {
  u32 u = __float_as_uint(f);
  u = (u + 0x7fffu + ((u >> 16) & 1u)) >> 16;  // RNE
  return (u16)u;
}
__device__ __forceinline__ float bf2f(u16 v) {
  return __uint_as_float(((u32)v) << 16);
}

__device__ __forceinline__ s16x8 load8cvt(const float* __restrict__ p) {
  float4 a = *(const float4*)p;
  float4 b = *(const float4*)(p + 4);
  s16x8 r;
  r[0] = (short)f2bf(a.x); r[1] = (short)f2bf(a.y);
  r[2] = (short)f2bf(a.z); r[3] = (short)f2bf(a.w);
  r[4] = (short)f2bf(b.x); r[5] = (short)f2bf(b.y);
  r[6] = (short)f2bf(b.z); r[7] = (short)f2bf(b.w);
  return r;
}

__device__ __forceinline__ s16x8 cvt2x4(float4 a, float4 b) {
  s16x8 r;
  r[0] = (short)f2bf(a.x); r[1] = (short)f2bf(a.y);
  r[2] = (short)f2bf(a.z); r[3] = (short)f2bf(a.w);
  r[4] = (short)f2bf(b.x); r[5] = (short)f2bf(b.y);
  r[6] = (short)f2bf(b.z); r[7] = (short)f2bf(b.w);
  return r;
}

// Fragment-linear index for a weight matrix W[N=96][K]:
// element W[o][k] -> ((kc*6 + nt)*64 + kg*16 + ln)*8 + j
__device__ __forceinline__ size_t wfrag_idx(int o, int k) {
  int kc = k >> 5, kg = (k >> 3) & 3, j = k & 7;
  int nt = o >> 4, ln = o & 15;
  return ((size_t)(kc * 6 + nt) * 64 + kg * 16 + ln) * 8 + j;
}

// ---------------------------------------------------------------------------
// Kernel 1 (prep1): conv-weight transposes (c3t[t][c][j], c5t[t][c][j]),
// q_w/v_w -> frag bf16, k_w conv-slices -> tiny frags kw3f/kw5f, b_eff.
// ---------------------------------------------------------------------------
__global__ __launch_bounds__(256) void prep1(
    const float* __restrict__ q_w, const float* __restrict__ k_w,
    const float* __restrict__ k_b, const float* __restrict__ v_w,
    const float* __restrict__ cn3_w, const float* __restrict__ cn3_b,
    const float* __restrict__ cn5_w, const float* __restrict__ cn5_b,
    float* __restrict__ c3t, float* __restrict__ c5t,
    u16* __restrict__ qwf, u16* __restrict__ vwf,
    u16* __restrict__ kw3f, u16* __restrict__ kw5f,
    float* __restrict__ beff) {
  int blk = blockIdx.x, tid = threadIdx.x;
  if (blk < 576) {                       // c3t: 147456
    int idx = blk * 256 + tid;
    int t = idx / (512 * 96);
    int rem = idx - t * 512 * 96;
    int c = rem / 96, j = rem - c * 96;
    c3t[idx] = cn3_w[(j * 512 + c) * 3 + t];
  } else if (blk < 1536) {               // c5t: 245760
    int idx = (blk - 576) * 256 + tid;
    int t = idx / (512 * 96);
    int rem = idx - t * 512 * 96;
    int c = rem / 96, j = rem - c * 96;
    c5t[idx] = cn5_w[(j * 512 + c) * 5 + t];
  } else if (blk < 1728) {               // qwf: 49152
    int e = (blk - 1536) * 256 + tid;
    int o = e >> 9, k = e & 511;
    qwf[wfrag_idx(o, k)] = f2bf(q_w[e]);
  } else if (blk < 2112) {               // vwf: 98304
    int e = (blk - 1728) * 256 + tid;
    int o = e >> 10, k = e & 1023;
    vwf[wfrag_idx(o, k)] = f2bf(v_w[e]);
  } else if (blk < 2184) {               // kw3f + kw5f: 2*9216
    int e = (blk - 2112) * 256 + tid;
    int half = e / 9216;
    int i = e - half * 9216;
    int o = i / 96, j = i - o * 96;
    float v = k_w[o * KCAT + (half ? 608 : 512) + j];
    size_t di = ((size_t)((j >> 5) * 6 + (o >> 4)) * 64 +
                 ((j >> 3) & 3) * 16 + (o & 15)) * 8 + (j & 7);
    (half ? kw5f : kw3f)[di] = f2bf(v);
  } else {                               // b_eff
    if (tid < 96) {
      const float* kwo = k_w + tid * KCAT;
      float b = k_b[tid];
      for (int j = 0; j < 96; ++j)
        b += kwo[512 + j] * cn3_b[j] + kwo[608 + j] * cn5_b[j];
      beff[tid] = b;
    }
  }
}

// ---------------------------------------------------------------------------
// Kernel 2 (prep2): W_eff fold as a GEMM (M=2560, N=96, K=96).
// ---------------------------------------------------------------------------
__global__ __launch_bounds__(256) void prep2(
    const float* __restrict__ c3t, const float* __restrict__ c5t,
    const u16* __restrict__ kw3f, const u16* __restrict__ kw5f,
    const float* __restrict__ k_w, u16* __restrict__ wefff) {
  __shared__ float Ls[4][16][100];
  int blk = blockIdx.x, tid = threadIdx.x;
  int wid = tid >> 6, lane = tid & 63, ln = lane & 15, kg = lane >> 4;
  int k = blk * 64 + wid * 16 + ln;
  bool c3ok = (k >= 512) && (k < 2048);
  const float* a5 = c5t + (size_t)k * 96;
  const float* a3 = c3t + (size_t)(c3ok ? k - 512 : 0) * 96;
  f32x4 acc[6];
  #pragma unroll
  for (int nt = 0; nt < 6; ++nt) acc[nt] = (f32x4){0.f, 0.f, 0.f, 0.f};
  #pragma unroll
  for (int jc = 0; jc < 3; ++jc) {
    s16x8 aa5 = load8cvt(a5 + jc * 32 + kg * 8);
    s16x8 aa3 = (s16x8){0, 0, 0, 0, 0, 0, 0, 0};
    if (c3ok) aa3 = load8cvt(a3 + jc * 32 + kg * 8);
    const u16* b5 = kw5f + (size_t)jc * 3072 + lane * 8;
    const u16* b3 = kw3f + (size_t)jc * 3072 + lane * 8;
    #pragma unroll
    for (int nt = 0; nt < 6; ++nt) {
      acc[nt] = __builtin_amdgcn_mfma_f32_16x16x32_bf16(
          aa5, *(const s16x8*)&b5[nt * 512], acc[nt], 0, 0, 0);
      acc[nt] = __builtin_amdgcn_mfma_f32_16x16x32_bf16(
          aa3, *(const s16x8*)&b3[nt * 512], acc[nt], 0, 0, 0);
    }
  }
  #pragma unroll
  for (int nt = 0; nt < 6; ++nt)
    #pragma unroll
    for (int r = 0; r < 4; ++r)
      Ls[wid][kg * 4 + r][nt * 16 + ln] = acc[nt][r];
  asm volatile("s_waitcnt lgkmcnt(0)" ::: "memory");
  #pragma unroll
  for (int sl = 0; sl < 3; ++sl) {
    int slot = sl * 64 + lane;
    int o = slot >> 1, rc = slot & 1;
    int k0 = blk * 64 + wid * 16 + rc * 8;
    int t = k0 >> 9, cbase = k0 & 511;
    s16x8 ov;
    #pragma unroll
    for (int e = 0; e < 8; ++e) {
      float v = Ls[wid][rc * 8 + e][o];
      if (t == 2) v += k_w[o * KCAT + cbase + e];
      ov[e] = (short)f2bf(v);
    }
    *(s16x8*)&wefff[((size_t)((k0 >> 5) * 6 + (o >> 4)) * 64 +
                     ((k0 >> 3) & 3) * 16 + (o & 15)) * 8] = ov;
  }
}

// ---------------------------------------------------------------------------
// Kernel 3: Q+K-conv and V projections FUSED into one launch.
// grid (64,8): blockIdx.x<32 -> QK path (bx), else V path (bx-32).
// Both: 64 rows/block, 4 waves x 16 rows, LDS-staged double-buffered A.
// ---------------------------------------------------------------------------
__global__ __launch_bounds__(256) void proj_fused(
    const float* __restrict__ evo, const float* __restrict__ plm,
    const u16* __restrict__ qwf, const u16* __restrict__ vwf,
    const u16* __restrict__ wefff, const float* __restrict__ q_b,
    const float* __restrict__ beff, const float* __restrict__ v_b,
    u16* __restrict__ Qf, u16* __restrict__ Kf,
    u16* __restrict__ Vfr, u16* __restrict__ Vb) {
  __shared__ u16 At[2 * 68 * 72];
  __shared__ float Ls[4][16][100];
  int bxr = blockIdx.x, bb = blockIdx.y;
  int tid = threadIdx.x;
  int wid = tid >> 6, lane = tid & 63, ln = lane & 15, kg = lane >> 4;
  int srow = tid >> 2, spart = tid & 3;

  if (bxr < 32) {
    // ---------------- QK path ----------------
    int bx = bxr;
    int r0 = bx * 64;
    const float* xb = evo + (size_t)bb * LSEQ * QIN;
    bool halo = tid < 16;
    int hrow = 64 + (tid >> 2);

    float4 ra0, ra1, ra2, ra3, rb0, rb1, rb2, rb3;
    auto LOADS = [&](int s) {
      int g = r0 - 2 + srow;
      if (g >= 0 && g < LSEQ) {
        const float* p = xb + (size_t)g * QIN + s * 64 + spart * 16;
        ra0 = *(const float4*)p;       ra1 = *(const float4*)(p + 4);
        ra2 = *(const float4*)(p + 8); ra3 = *(const float4*)(p + 12);
      } else {
        ra0 = ra1 = ra2 = ra3 = make_float4(0.f, 0.f, 0.f, 0.f);
      }
      if (halo) {
        int g2 = r0 - 2 + hrow;
        if (g2 < LSEQ) {
          const float* p = xb + (size_t)g2 * QIN + s * 64 + spart * 16;
          rb0 = *(const float4*)p;       rb1 = *(const float4*)(p + 4);
          rb2 = *(const float4*)(p + 8); rb3 = *(const float4*)(p + 12);
        } else {
          rb0 = rb1 = rb2 = rb3 = make_float4(0.f, 0.f, 0.f, 0.f);
        }
      }
    };
    auto WRITES = [&](int buf) {
      u16* d = &At[(buf * 68 + srow) * 72 + spart * 16];
      *(s16x8*)d = cvt2x4(ra0, ra1);
      *(s16x8*)(d + 8) = cvt2x4(ra2, ra3);
      if (halo) {
        u16* d2 = &At[(buf * 68 + hrow) * 72 + spart * 16];
        *(s16x8*)d2 = cvt2x4(rb0, rb1);
        *(s16x8*)(d2 + 8) = cvt2x4(rb2, rb3);
      }
    };

    f32x4 accQ[6], accK[6];
    #pragma unroll
    for (int nt = 0; nt < 6; ++nt) {
      accQ[nt] = (f32x4){0.f, 0.f, 0.f, 0.f};
      accK[nt] = (f32x4){0.f, 0.f, 0.f, 0.f};
    }

    LOADS(0);
    WRITES(0);
    __syncthreads();
    int cur = 0;
    for (int s = 0; s < 8; ++s) {
      if (s < 7) LOADS(s + 1);
      #pragma unroll
      for (int cc = 0; cc < 2; ++cc) {
        int colb = cc * 32 + kg * 8;
        int kcg = s * 2 + cc;
        const u16* arow = &At[(cur * 68 + wid * 16 + ln) * 72 + colb];
        s16x8 aQ = *(const s16x8*)&arow[2 * 72];
        const u16* bq = qwf + (size_t)kcg * 3072 + lane * 8;
        #pragma unroll
        for (int nt = 0; nt < 6; ++nt)
          accQ[nt] = __builtin_amdgcn_mfma_f32_16x16x32_bf16(
              aQ, *(const s16x8*)&bq[nt * 512], accQ[nt], 0, 0, 0);
        #pragma unroll
        for (int t = 0; t < 5; ++t) {
          s16x8 aK = *(const s16x8*)&arow[t * 72];
          const u16* bk = wefff + (size_t)(t * 16 + kcg) * 3072 + lane * 8;
          #pragma unroll
          for (int nt = 0; nt < 6; ++nt)
            accK[nt] = __builtin_amdgcn_mfma_f32_16x16x32_bf16(
                aK, *(const s16x8*)&bk[nt * 512], accK[nt], 0, 0, 0);
        }
      }
      if (s < 7) {
        WRITES(cur ^ 1);
        __syncthreads();
        cur ^= 1;
      }
    }

    size_t qt = (size_t)bb * 128 + bx * 4 + wid;
    #pragma unroll
    for (int nt = 0; nt < 6; ++nt)
      #pragma unroll
      for (int r = 0; r < 4; ++r)
        Ls[wid][kg * 4 + r][nt * 16 + ln] = accQ[nt][r];
    asm volatile("s_waitcnt lgkmcnt(0)" ::: "memory");
    #pragma unroll
    for (int sl = 0; sl < 3; ++sl) {
      int slot = sl * 64 + lane;
      int r = slot / 12, cg = slot % 12;
      s16x8 ov;
      #pragma unroll
      for (int e = 0; e < 8; ++e) {
        int c = cg * 8 + e;
        ov[e] = (short)f2bf(Ls[wid][r][c] + q_b[c]);
      }
      *(s16x8*)&Qf[((qt * 3 + (cg >> 2)) * 64 + (cg & 3) * 16 + r) * 8] = ov;
    }
    asm volatile("s_waitcnt lgkmcnt(0) vmcnt(0)" ::: "memory");
    #pragma unroll
    for (int nt = 0; nt < 6; ++nt)
      #pragma unroll
      for (int r = 0; r < 4; ++r)
        Ls[wid][kg * 4 + r][nt * 16 + ln] = accK[nt][r];
    asm volatile("s_waitcnt lgkmcnt(0)" ::: "memory");
    #pragma unroll
    for (int sl = 0; sl < 3; ++sl) {
      int slot = sl * 64 + lane;
      int r = slot / 12, cg = slot % 12;
      s16x8 ov;
      #pragma unroll
      for (int e = 0; e < 8; ++e) {
        int c = cg * 8 + e;
        ov[e] = (short)f2bf(Ls[wid][r][c] + beff[c]);
      }
      *(s16x8*)&Kf[((qt * 3 + (cg >> 2)) * 64 + (cg & 3) * 16 + r) * 8] = ov;
    }
  } else {
    // ---------------- V path ----------------
    int bx = bxr - 32;
    const float* xb = plm + ((size_t)bb * LSEQ + bx * 64) * VIN;
    float4 ra0, ra1, ra2, ra3;
    auto LOADS = [&](int s) {
      const float* p = xb + (size_t)srow * VIN + s * 64 + spart * 16;
      ra0 = *(const float4*)p;       ra1 = *(const float4*)(p + 4);
      ra2 = *(const float4*)(p + 8); ra3 = *(const float4*)(p + 12);
    };
    auto WRITES = [&](int buf) {
      u16* d = &At[(buf * 68 + srow) * 72 + spart * 16];
      *(s16x8*)d = cvt2x4(ra0, ra1);
      *(s16x8*)(d + 8) = cvt2x4(ra2, ra3);
    };

    f32x4 acc[6];
    #pragma unroll
    for (int nt = 0; nt < 6; ++nt) acc[nt] = (f32x4){0.f, 0.f, 0.f, 0.f};

    LOADS(0);
    WRITES(0);
    __syncthreads();
    int cur = 0;
    for (int s = 0; s < 16; ++s) {
      if (s < 15) LOADS(s + 1);
      #pragma unroll
      for (int cc = 0; cc < 2; ++cc) {
        int colb = cc * 32 + kg * 8;
        int kcg = s * 2 + cc;
        s16x8 a = *(const s16x8*)&At[(cur * 68 + wid * 16 + ln) * 72 + colb];
        const u16* bv = vwf + (size_t)kcg * 3072 + lane * 8;
        #pragma unroll
        for (int nt = 0; nt < 6; ++nt)
          acc[nt] = __builtin_amdgcn_mfma_f32_16x16x32_bf16(
              a, *(const s16x8*)&bv[nt * 512], acc[nt], 0, 0, 0);
      }
      if (s < 15) {
        WRITES(cur ^ 1);
        __syncthreads();
        cur ^= 1;
      }
    }

    #pragma unroll
    for (int nt = 0; nt < 6; ++nt)
      #pragma unroll
      for (int r = 0; r < 4; ++r)
        Ls[wid][kg * 4 + r][nt * 16 + ln] = acc[nt][r];
    asm volatile("s_waitcnt lgkmcnt(0)" ::: "memory");
    #pragma unroll
    for (int sl = 0; sl < 3; ++sl) {
      int slot = sl * 64 + lane;
      int r = slot / 12, cg = slot % 12;
      s16x8 ov;
      #pragma unroll
      for (int e = 0; e < 8; ++e) {
        int c = cg * 8 + e;
        ov[e] = (short)f2bf(Ls[wid][r][c] + v_b[c]);
      }
      *(s16x8*)&Vb[((size_t)bb * LSEQ + bx * 64 + wid * 16 + r) * 96 + cg * 8] = ov;
    }
    #pragma unroll
    for (int sl = 0; sl < 3; ++sl) {
      int slot = sl * 64 + lane;
      int c = slot >> 1, rc = slot & 1;
      int key0 = bx * 64 + wid * 16 + rc * 8;
      s16x8 fv;
      #pragma unroll
      for (int e = 0; e < 8; ++e)
        fv[e] = (short)f2bf(Ls[wid][rc * 8 + e][c] + v_b[c]);
      *(s16x8*)&Vfr[(((size_t)bb * 64 + (key0 >> 5)) * 6 + (c >> 4)) * 512 +
                    (((key0 >> 3) & 3) * 16 + (c & 15)) * 8] = fv;
    }
  }
}

// ---------------------------------------------------------------------------
// Kernel 4: flash attention + "+V".  Batch-interleaved bid mapping (every
// XCD sees all 8 batches) + K-fragment register prefetch across kc-steps.
// ---------------------------------------------------------------------------
__global__ __launch_bounds__(256, 4) void attn_kernel(
    const u16* __restrict__ Qf, const u16* __restrict__ Kf,
    const u16* __restrict__ Vfr, const u16* __restrict__ Vb,
    const int* __restrict__ seqlen, float* __restrict__ out) {
  __shared__ u16 Ps[4][16][40];
  __shared__ float Cacc[4][16][97];
  __shared__ float Cml[4][16][2];

  int bid = blockIdx.x;
  int bb = (bid >> 3) & 7;                      // batch varies within an XCD
  int bx = ((bid >> 6) << 3) | (bid & 7);       // q-tile
  int tid = threadIdx.x;
  int wid = tid >> 6, lane = tid & 63, ln = lane & 15, kg = lane >> 4;
  int n = seqlen[bb];
  int nkc = (n + 31) >> 5;

  size_t qt = (size_t)bb * 128 + bx;
  s16x8 aQ[3];
  #pragma unroll
  for (int kk = 0; kk < 3; ++kk)
    aQ[kk] = *(const s16x8*)&Qf[((qt * 3 + kk) * 64 + lane) * 8];

  float m[4], lsum[4];
  f32x4 acc[6];
  #pragma unroll
  for (int r = 0; r < 4; ++r) { m[r] = -1e30f; lsum[r] = 0.f; }
  #pragma unroll
  for (int nt = 0; nt < 6; ++nt) acc[nt] = (f32x4){0.f, 0.f, 0.f, 0.f};

  const u16* Kbb = Kf + (size_t)bb * 128 * 1536;
  s16x8 kf[6];
  {
    int k0 = (wid < nkc) ? wid : 0;
    const u16* kp = Kbb + (size_t)k0 * 3072 + lane * 8;
    #pragma unroll
    for (int i = 0; i < 6; ++i) kf[i] = *(const s16x8*)&kp[i * 512];
  }

  for (int kc = wid; kc < nkc; kc += 4) {
    int key0 = kc * 32;
    f32x4 s0 = (f32x4){0.f, 0.f, 0.f, 0.f};
    f32x4 s1 = (f32x4){0.f, 0.f, 0.f, 0.f};
    #pragma unroll
    for (int kk = 0; kk < 3; ++kk) {
      s0 = __builtin_amdgcn_mfma_f32_16x16x32_bf16(aQ[kk], kf[kk], s0, 0, 0, 0);
      s1 = __builtin_amdgcn_mfma_f32_16x16x32_bf16(aQ[kk], kf[3 + kk], s1, 0, 0, 0);
    }

    // prefetch next K tile (hides L2 latency under softmax)
    s16x8 kf2[6];
    {
      int kn = (kc + 4 < nkc) ? kc + 4 : 0;
      const u16* kp = Kbb + (size_t)kn * 3072 + lane * 8;
      #pragma unroll
      for (int i = 0; i < 6; ++i) kf2[i] = *(const s16x8*)&kp[i * 512];
    }

    bool v0 = (key0 + ln) < n;
    bool v1 = (key0 + 16 + ln) < n;
    float sv0[4], sv1[4], mx[4];
    #pragma unroll
    for (int r = 0; r < 4; ++r) {
      sv0[r] = v0 ? s0[r] * NORMS : -1e30f;
      sv1[r] = v1 ? s1[r] * NORMS : -1e30f;
      mx[r] = fmaxf(sv0[r], sv1[r]);
    }
    #pragma unroll
    for (int r = 0; r < 4; ++r) {
      mx[r] = fmaxf(mx[r], __shfl_xor(mx[r], 1, 16));
      mx[r] = fmaxf(mx[r], __shfl_xor(mx[r], 2, 16));
      mx[r] = fmaxf(mx[r], __shfl_xor(mx[r], 4, 16));
      mx[r] = fmaxf(mx[r], __shfl_xor(mx[r], 8, 16));
    }
    float p0[4], p1[4], rs[4];
    bool defer = __all((mx[0] <= m[0] + 8.f) && (mx[1] <= m[1] + 8.f) &&
                       (mx[2] <= m[2] + 8.f) && (mx[3] <= m[3] + 8.f));
    if (defer) {
      #pragma unroll
      for (int r = 0; r < 4; ++r) {
        p0[r] = __expf(sv0[r] - m[r]);
        p1[r] = __expf(sv1[r] - m[r]);
        rs[r] = p0[r] + p1[r];
      }
      #pragma unroll
      for (int r = 0; r < 4; ++r) {
        rs[r] += __shfl_xor(rs[r], 1, 16);
        rs[r] += __shfl_xor(rs[r], 2, 16);
        rs[r] += __shfl_xor(rs[r], 4, 16);
        rs[r] += __shfl_xor(rs[r], 8, 16);
        lsum[r] += rs[r];
      }
    } else {
      float fac[4];
      #pragma unroll
      for (int r = 0; r < 4; ++r) {
        float mn = fmaxf(m[r], mx[r]);
        fac[r] = __expf(m[r] - mn);
        p0[r] = __expf(sv0[r] - mn);
        p1[r] = __expf(sv1[r] - mn);
        rs[r] = p0[r] + p1[r];
        m[r] = mn;
      }
      #pragma unroll
      for (int r = 0; r < 4; ++r) {
        rs[r] += __shfl_xor(rs[r], 1, 16);
        rs[r] += __shfl_xor(rs[r], 2, 16);
        rs[r] += __shfl_xor(rs[r], 4, 16);
        rs[r] += __shfl_xor(rs[r], 8, 16);
        lsum[r] = lsum[r] * fac[r] + rs[r];
      }
      #pragma unroll
      for (int nt = 0; nt < 6; ++nt)
        #pragma unroll
        for (int r = 0; r < 4; ++r) acc[nt][r] *= fac[r];
    }

    u16* Pw = &Ps[wid][0][0];
    #pragma unroll
    for (int r = 0; r < 4; ++r) {
      Pw[(kg * 4 + r) * 40 + ln] = f2bf(p0[r]);
      Pw[(kg * 4 + r) * 40 + 16 + ln] = f2bf(p1[r]);
    }
    s16x8 pa = *(const s16x8*)&Pw[ln * 40 + kg * 8];

    const u16* vf = Vfr + (((size_t)bb * 64 + kc) * 6 * 64) * 8 + lane * 8;
    #pragma unroll
    for (int nt = 0; nt < 6; ++nt) {
      s16x8 bv = *(const s16x8*)&vf[(size_t)nt * 512];
      acc[nt] = __builtin_amdgcn_mfma_f32_16x16x32_bf16(pa, bv, acc[nt], 0, 0, 0);
    }
    #pragma unroll
    for (int i = 0; i < 6; ++i) kf[i] = kf2[i];
  }

  #pragma unroll
  for (int nt = 0; nt < 6; ++nt)
    #pragma unroll
    for (int r = 0; r < 4; ++r)
      Cacc[wid][kg * 4 + r][nt * 16 + ln] = acc[nt][r];
  if (ln == 0) {
    #pragma unroll
    for (int r = 0; r < 4; ++r) {
      Cml[wid][kg * 4 + r][0] = m[r];
      Cml[wid][kg * 4 + r][1] = lsum[r];
    }
  }
  __syncthreads();

  size_t obase = ((size_t)bb * LSEQ + bx * 16) * 96;
  for (int i = tid; i < 1536; i += 256) {
    int row = i / 96;
    float mg = -1e30f;
    #pragma unroll
    for (int w = 0; w < 4; ++w) mg = fmaxf(mg, Cml[w][row][0]);
    float lg = 0.f, av = 0.f;
    #pragma unroll
    for (int w = 0; w < 4; ++w) {
      float e = __expf(Cml[w][row][0] - mg);
      lg += Cml[w][row][1] * e;
      av += Cacc[w][row][i - row * 96] * e;
    }
    out[obase + i] = av / lg + bf2f(Vb[obase + i]);
  }
}

// ---------------------------------------------------------------------------
extern "C" void kernel_launch(void* const* d_in, const int* in_sizes, int n_in,
                              void* d_out, int out_size, void* d_ws,
                              size_t ws_size, hipStream_t stream) {
  const float* plm   = (const float*)d_in[0];
  const float* evo   = (const float*)d_in[1];
  const int* seqlen  = (const int*)d_in[2];
  const float* q_w   = (const float*)d_in[3];
  const float* q_b   = (const float*)d_in[4];
  const float* k_w   = (const float*)d_in[5];
  const float* k_b   = (const float*)d_in[6];
  const float* v_w   = (const float*)d_in[7];
  const float* v_b   = (const float*)d_in[8];
  const float* cn3_w = (const float*)d_in[9];
  const float* cn3_b = (const float*)d_in[10];
  const float* cn5_w = (const float*)d_in[11];
  const float* cn5_b = (const float*)d_in[12];

  char* ws = (char*)d_ws;
  u16* wefff  = (u16*)(ws + 0);           // 491520
  float* beff = (float*)(ws + 491520);    // 512
  u16* qwf    = (u16*)(ws + 492032);      // 98304
  u16* vwf    = (u16*)(ws + 590336);      // 196608
  float* c3t  = (float*)(ws + 786944);    // 589824
  float* c5t  = (float*)(ws + 1376768);   // 983040
  u16* kw3f   = (u16*)(ws + 2359808);     // 18432
  u16* kw5f   = (u16*)(ws + 2378240);     // 18432
  u16* Qf     = (u16*)(ws + 2396672);     // 3145728
  u16* Kf     = (u16*)(ws + 5542400);     // 3145728
  u16* Vfr    = (u16*)(ws + 8688128);     // 3145728
  u16* Vb     = (u16*)(ws + 11833856);    // 3145728
  float* out  = (float*)d_out;

  prep1<<<2185, 256, 0, stream>>>(q_w, k_w, k_b, v_w, cn3_w, cn3_b, cn5_w,
                                  cn5_b, c3t, c5t, qwf, vwf, kw3f, kw5f, beff);
  prep2<<<40, 256, 0, stream>>>(c3t, c5t, kw3f, kw5f, k_w, wefff);
  proj_fused<<<dim3(64, 8), 256, 0, stream>>>(evo, plm, qwf, vwf, wefff,
                                              q_b, beff, v_b, Qf, Kf, Vfr, Vb);
  attn_kernel<<<1024, 256, 0, stream>>>(Qf, Kf, Vfr, Vb, seqlen, out);
}